// Round 6
// baseline (598.999 us; speedup 1.0000x reference)
//
#include <hip/hip_runtime.h>
#include <hip/hip_fp16.h>

#define NB 32
#define N 512
#define MAT (N*N)   // 262144

typedef _Float16 half8 __attribute__((ext_vector_type(8)));
typedef float f32x4 __attribute__((ext_vector_type(4)));

#define MSCALE 2048.0f
#define RMSCALE (1.0f/2048.0f)

__device__ inline ushort2 split2(float x) {
    __half h = __float2half(x);
    __half m = __float2half((x - __half2float(h)) * MSCALE);
    return make_ushort2(__half_as_ushort(h), __half_as_ushort(m));
}

__device__ inline void gload(const ushort* g, ushort* l) {
    __builtin_amdgcn_global_load_lds((const __attribute__((address_space(1))) void*)g,
                                     (__attribute__((address_space(3))) void*)l, 16, 0, 0);
}

// ---------------- luma + transpose -> yT fp16 planes (staged in d_out) ----------------
__global__ __launch_bounds__(256) void k_luma(const float* __restrict__ x,
                                              ushort* __restrict__ Ph, ushort* __restrict__ Pm) {
    int b = blockIdx.y;
    int tile = blockIdx.x;
    int TR = (tile >> 3) * 64;
    int TC = (tile & 7) * 64;
    __shared__ float ld[64][65];
    int t = threadIdx.x;
    int r0 = t >> 4;
    int c4 = (t & 15) * 4;
    const float* xb = x + (size_t)b * 3 * MAT;
    #pragma unroll
    for (int q = 0; q < 4; ++q) {
        int row = r0 + q * 16;
        size_t off = (size_t)(TR + row) * N + TC + c4;
        float4 rr = *(const float4*)&xb[off];
        float4 gg = *(const float4*)&xb[off + MAT];
        float4 bb = *(const float4*)&xb[off + 2 * MAT];
        ld[row][c4 + 0] = 0.299f * rr.x + 0.587f * gg.x + 0.114f * bb.x;
        ld[row][c4 + 1] = 0.299f * rr.y + 0.587f * gg.y + 0.114f * bb.y;
        ld[row][c4 + 2] = 0.299f * rr.z + 0.587f * gg.z + 0.114f * bb.z;
        ld[row][c4 + 3] = 0.299f * rr.w + 0.587f * gg.w + 0.114f * bb.w;
    }
    __syncthreads();
    ushort* PhB = Ph + (size_t)b * MAT;
    ushort* PmB = Pm + (size_t)b * MAT;
    #pragma unroll
    for (int q = 0; q < 4; ++q) {
        int i = r0 + q * 16;
        float v0 = ld[c4 + 0][i];
        float v1 = ld[c4 + 1][i];
        float v2 = ld[c4 + 2][i];
        float v3 = ld[c4 + 3][i];
        size_t off = (size_t)(TC + i) * N + TR + c4;
        ushort2 s0 = split2(v0), s1 = split2(v1), s2 = split2(v2), s3 = split2(v3);
        *(ushort4*)&PhB[off] = make_ushort4(s0.x, s1.x, s2.x, s3.x);
        *(ushort4*)&PmB[off] = make_ushort4(s0.y, s1.y, s2.y, s3.y);
    }
}

// ---------------- triangular MFMA GEMM: C = alpha * P * P^T (symmetric output) ----------------
// Grid.x = 10 lower-triangle 128x128 tiles; off-diag tiles mirrored at store.
// NPIN=2: hi+mid planes, 3 MFMA products. NPIN=1: h plane, 1 product.
template<int NPIN>
__global__ __launch_bounds__(256, 2) void k_gemm(const ushort* __restrict__ Ph, const ushort* __restrict__ Pm,
                                                 ushort* __restrict__ Qh, ushort* __restrict__ Qm,
                                                 const float* __restrict__ fsrc, float* __restrict__ fdst) {
    int b = blockIdx.y;
    const ushort* PhB = Ph + (size_t)b * MAT;
    const ushort* PmB = (NPIN == 2) ? Pm + (size_t)b * MAT : nullptr;

    __shared__ __align__(16) ushort sI[NPIN][128 * 32];
    __shared__ __align__(16) ushort sJ[NPIN][128 * 32];

    int t = threadIdx.x;
    // triangular tile index -> (ti >= tj)
    int tile = blockIdx.x;
    int ti = 0;
    while ((ti + 1) * (ti + 2) / 2 <= tile) ++ti;
    int tj = tile - ti * (ti + 1) / 2;
    int iBase = ti * 128, jBase = tj * 128;
    bool diag = (ti == tj);

    int lane = t & 63, wv = t >> 6;
    int wi = wv >> 1, wj = wv & 1;
    int cc = lane & 15, cq = lane >> 4;
    int q8 = cq * 8;
    int lrow = lane >> 2;
    int lseg = lane & 3;

    float alpha = fsrc ? (1.0f / fsrc[b]) : 1.0f;

    f32x4 acc0[4][4], acc1[4][4];
    #pragma unroll
    for (int i = 0; i < 4; ++i)
        #pragma unroll
        for (int j = 0; j < 4; ++j) { acc0[i][j] = (f32x4)0.f; acc1[i][j] = (f32x4)0.f; }

    for (int k0 = 0; k0 < N; k0 += 32) {
        if (NPIN == 2) {
            if (diag) {
                #pragma unroll
                for (int j = 0; j < 4; ++j) {
                    int q = wv * 4 + j;
                    int pl = q >> 3, rg = q & 7;
                    const ushort* src = (pl ? PmB : PhB) + (size_t)(iBase + rg * 16 + lrow) * N + k0 + lseg * 8;
                    gload(src, &sI[pl][rg * 512]);
                }
            } else {
                #pragma unroll
                for (int j = 0; j < 8; ++j) {
                    int q = wv * 8 + j;
                    int panel = q >> 4, pl = (q >> 3) & 1, rg = q & 7;
                    int rb = panel ? jBase : iBase;
                    const ushort* src = (pl ? PmB : PhB) + (size_t)(rb + rg * 16 + lrow) * N + k0 + lseg * 8;
                    gload(src, panel ? &sJ[pl][rg * 512] : &sI[pl][rg * 512]);
                }
            }
        } else {
            if (diag) {
                #pragma unroll
                for (int j = 0; j < 2; ++j) {
                    int rg = wv * 2 + j;
                    const ushort* src = PhB + (size_t)(iBase + rg * 16 + lrow) * N + k0 + lseg * 8;
                    gload(src, &sI[0][rg * 512]);
                }
            } else {
                #pragma unroll
                for (int j = 0; j < 4; ++j) {
                    int q = wv * 4 + j;
                    int panel = q >> 3, rg = q & 7;
                    int rb = panel ? jBase : iBase;
                    const ushort* src = PhB + (size_t)(rb + rg * 16 + lrow) * N + k0 + lseg * 8;
                    gload(src, panel ? &sJ[0][rg * 512] : &sI[0][rg * 512]);
                }
            }
        }
        __syncthreads();

        const ushort(*Jb)[128 * 32] = diag ? sI : sJ;

        half8 bh[4], bm[4];
        #pragma unroll
        for (int ct = 0; ct < 4; ++ct) {
            int row = wj * 64 + ct * 16 + cc;
            bh[ct] = *(const half8*)&Jb[0][row * 32 + q8];
            if (NPIN == 2) bm[ct] = *(const half8*)&Jb[1][row * 32 + q8];
        }
        #pragma unroll
        for (int rt = 0; rt < 4; ++rt) {
            int row = wi * 64 + rt * 16 + cc;
            half8 ah = *(const half8*)&sI[0][row * 32 + q8];
            half8 am;
            if (NPIN == 2) am = *(const half8*)&sI[1][row * 32 + q8];
            #pragma unroll
            for (int ct = 0; ct < 4; ++ct) {
                acc0[rt][ct] = __builtin_amdgcn_mfma_f32_16x16x32_f16(ah, bh[ct], acc0[rt][ct], 0, 0, 0);
                if (NPIN == 2) {
                    acc1[rt][ct] = __builtin_amdgcn_mfma_f32_16x16x32_f16(ah, bm[ct], acc1[rt][ct], 0, 0, 0);
                    acc1[rt][ct] = __builtin_amdgcn_mfma_f32_16x16x32_f16(am, bh[ct], acc1[rt][ct], 0, 0, 0);
                }
            }
        }
        __syncthreads();
    }

    ushort* QhB = Qh + (size_t)b * MAT;
    ushort* QmB = Qm ? Qm + (size_t)b * MAT : nullptr;
    float ss = 0.f;
    #pragma unroll
    for (int rt = 0; rt < 4; ++rt) {
        int i0 = iBase + wi * 64 + rt * 16 + cq * 4;
        #pragma unroll
        for (int ct = 0; ct < 4; ++ct) {
            int j0 = jBase + wj * 64 + ct * 16 + cc;
            #pragma unroll
            for (int r = 0; r < 4; ++r) {
                float o = acc0[rt][ct][r];
                if (NPIN == 2) o += acc1[rt][ct][r] * RMSCALE;
                o *= alpha;
                ss += o * o;
                size_t idx = (size_t)(i0 + r) * N + j0;
                size_t idxT = (size_t)j0 * N + (i0 + r);
                if (QmB) {
                    ushort2 hm = split2(o);
                    QhB[idx] = hm.x;
                    QmB[idx] = hm.y;
                    if (!diag) { QhB[idxT] = hm.x; QmB[idxT] = hm.y; }
                } else {
                    ushort hv = __half_as_ushort(__float2half(o));
                    QhB[idx] = hv;
                    if (!diag) QhB[idxT] = hv;
                }
            }
        }
    }

    if (fdst) {
        if (!diag) ss *= 2.f;
        for (int o = 32; o; o >>= 1) ss += __shfl_down(ss, o, 64);
        __shared__ float red[4];
        if (lane == 0) red[wv] = ss;
        __syncthreads();
        if (t == 0) atomicAdd(&fdst[b], red[0] + red[1] + red[2] + red[3]);
    }
}

// ---------------- power iteration on symmetric fp16 C (=B^512), then w via yT h-plane ----------------
__global__ __launch_bounds__(512) void k_power(const ushort* __restrict__ Ch, const ushort* __restrict__ Yh,
                                               float* __restrict__ vout, float* __restrict__ wout, int iters) {
    int b = blockIdx.x;
    const __half* C = (const __half*)(Ch + (size_t)b * MAT);
    const __half* Yt = (const __half*)(Yh + (size_t)b * MAT);
    __shared__ __align__(16) float va[N];
    __shared__ __align__(16) float vb[N];
    __shared__ float red[8];
    __shared__ float snorm;
    int t = threadIdx.x, lane = t & 63, wv = t >> 6;

    unsigned h = (unsigned)t * 1103515245u + 12345u;
    va[t] = (float)((h >> 16) & 0x7fff) / 16384.f - 1.f;
    __syncthreads();

    const __half* Ct = C + t;
    for (int it = 0; it < iters; ++it) {
        float* src = (it & 1) ? vb : va;
        float* dst = (it & 1) ? va : vb;
        float acc = 0.f;
        #pragma unroll 4
        for (int c = 0; c < N; c += 8) {
            float4 s0 = *(const float4*)&src[c];
            float4 s1 = *(const float4*)&src[c + 4];
            const __half* p = Ct + (size_t)c * N;
            acc += __half2float(p[0 * N]) * s0.x;
            acc += __half2float(p[1 * N]) * s0.y;
            acc += __half2float(p[2 * N]) * s0.z;
            acc += __half2float(p[3 * N]) * s0.w;
            acc += __half2float(p[4 * N]) * s1.x;
            acc += __half2float(p[5 * N]) * s1.y;
            acc += __half2float(p[6 * N]) * s1.z;
            acc += __half2float(p[7 * N]) * s1.w;
        }
        float ss = acc * acc;
        for (int o = 32; o; o >>= 1) ss += __shfl_xor(ss, o, 64);
        if (lane == 0) red[wv] = ss;
        __syncthreads();
        if (t == 0) {
            float tt = 0.f;
            #pragma unroll
            for (int i = 0; i < 8; ++i) tt += red[i];
            snorm = rsqrtf(tt);
        }
        __syncthreads();
        dst[t] = acc * snorm;
        __syncthreads();
    }

    float* fin = (iters & 1) ? vb : va;
    const __half* Ytt = Yt + t;
    float accw = 0.f;
    #pragma unroll 4
    for (int c = 0; c < N; c += 8) {
        float4 s0 = *(const float4*)&fin[c];
        float4 s1 = *(const float4*)&fin[c + 4];
        const __half* p = Ytt + (size_t)c * N;
        accw += __half2float(p[0 * N]) * s0.x;
        accw += __half2float(p[1 * N]) * s0.y;
        accw += __half2float(p[2 * N]) * s0.z;
        accw += __half2float(p[3 * N]) * s0.w;
        accw += __half2float(p[4 * N]) * s1.x;
        accw += __half2float(p[5 * N]) * s1.y;
        accw += __half2float(p[6 * N]) * s1.z;
        accw += __half2float(p[7 * N]) * s1.w;
    }
    vout[(size_t)b * N + t] = fin[t];
    wout[(size_t)b * N + t] = accw;
}

// ---------------- out[b,i,j] = w[b,i] * v[b,j] ----------------
__global__ __launch_bounds__(256) void k_outer(const float* __restrict__ v, const float* __restrict__ w,
                                               float* __restrict__ out) {
    int tid = blockIdx.x * 256 + threadIdx.x;
    int b = tid >> 16;
    int rem = tid & 65535;
    int i = rem >> 7;
    int j4 = rem & 127;
    float wi = w[(size_t)b * N + i];
    float4 vv = ((const float4*)(v + (size_t)b * N))[j4];
    float4 o = {wi * vv.x, wi * vv.y, wi * vv.z, wi * vv.w};
    ((float4*)out)[tid] = o;
}

extern "C" void kernel_launch(void* const* d_in, const int* in_sizes, int n_in,
                              void* d_out, int out_size, void* d_ws, size_t ws_size,
                              hipStream_t stream) {
    const float* x = (const float*)d_in[0];
    float* out = (float*)d_out;
    char* base = (char*)d_ws;

    const size_t PL = (size_t)NB * MAT * sizeof(ushort);   // 16 MB per plane array
    ushort* AH = (ushort*)(base);
    ushort* AM = (ushort*)(base + PL);
    ushort* BH = (ushort*)(base + 2 * PL);
    ushort* BM = (ushort*)(base + 3 * PL);
    float*  fs = (float*)(base + 4 * PL);
    float*  vv = fs + 512;
    float*  ww = vv + (size_t)NB * N;
    // yT fp16 planes staged in d_out (exactly 32 MB): h at base, m at +16MB
    ushort* YH = (ushort*)out;
    ushort* YM = YH + (size_t)NB * MAT;

    hipMemsetAsync(fs, 0, 512 * sizeof(float), stream);
    k_luma<<<dim3(64, NB), 256, 0, stream>>>(x, YH, YM);

    dim3 gg(10, NB);   // 10 lower-triangle tiles x batches
    k_gemm<2><<<gg, 256, 0, stream>>>(YH, YM, BH, BM,      nullptr,   fs + 0*32); // B      = yT yT^T
    k_gemm<2><<<gg, 256, 0, stream>>>(BH, BM, AH, AM,      fs + 0*32, fs + 1*32); // B^2
    k_gemm<2><<<gg, 256, 0, stream>>>(AH, AM, BH, nullptr, fs + 1*32, fs + 2*32); // B^4   (h only)
    k_gemm<1><<<gg, 256, 0, stream>>>(BH, nullptr, AH, nullptr, fs + 2*32, fs + 3*32); // B^8
    k_gemm<1><<<gg, 256, 0, stream>>>(AH, nullptr, BH, nullptr, fs + 3*32, fs + 4*32); // B^16
    k_gemm<1><<<gg, 256, 0, stream>>>(BH, nullptr, AH, nullptr, fs + 4*32, fs + 5*32); // B^32
    k_gemm<1><<<gg, 256, 0, stream>>>(AH, nullptr, BH, nullptr, fs + 5*32, fs + 6*32); // B^64
    k_gemm<1><<<gg, 256, 0, stream>>>(BH, nullptr, AH, nullptr, fs + 6*32, fs + 7*32); // B^128
    k_gemm<1><<<gg, 256, 0, stream>>>(AH, nullptr, BH, nullptr, fs + 7*32, fs + 8*32); // B^256
    k_gemm<1><<<gg, 256, 0, stream>>>(BH, nullptr, AH, nullptr, fs + 8*32, nullptr);   // B^512 -> AH

    k_power<<<NB, 512, 0, stream>>>(AH, YH, vv, ww, 4);
    k_outer<<<8192, 256, 0, stream>>>(vv, ww, out);
}